// Round 6
// baseline (26569.800 us; speedup 1.0000x reference)
//
#include <hip/hip_runtime.h>
#include <hip/hip_bf16.h>
#include <math.h>

#define L_  2
#define H_  512
#define D_  512
#define B_  64
#define T_  512
#define NSTEP (T_ + 1)

typedef __attribute__((ext_vector_type(8))) __bf16  bf16x8;
typedef __attribute__((ext_vector_type(4))) float   f32x4;

union FragU { uint4 u; bf16x8 v; };

// ---- workspace layout (byte offsets) --------------------------------------
#define OFF_WP    0
#define OFF_INTB  (16777216)
#define OFF_HBF   (16777216 + 33554432)
#define OFF_CF32  (OFF_HBF + 524288)
#define OFF_HF32  (OFF_CF32 + 524288)
#define OFF_BIAS  (OFF_HF32 + 524288)
#define OFF_BAR   (OFF_BIAS + 32768)

__device__ __forceinline__ int hoff(int dir, int lay, int par) {
    return (((dir * 2 + lay) * 2 + par)) * (B_ * H_);   // bf16 elements
}

// ---------------------------------------------------------------------------
// Pack weights into MFMA fragment order, bf16.
// Wp[((((cell*32+hct)*4+g)*32+ks)*64+l)*8 + j] =
//   W[cell][g*512 + hct*16 + (l&15)][ks*32 + (l>>4)*8 + j], W = [Wih | Whh]
// ---------------------------------------------------------------------------
__global__ void prep_weights(const float* __restrict__ Wih_f, const float* __restrict__ Whh_f,
                             const float* __restrict__ Wih_b, const float* __restrict__ Whh_b,
                             __hip_bfloat16* __restrict__ Wp) {
    int tid = blockIdx.x * blockDim.x + threadIdx.x;     // 0 .. 1048575
    int l    = tid & 63;
    int g    = (tid >> 11) & 3;
    int hct  = (tid >> 13) & 31;
    int cell = tid >> 18;
    int dir  = cell >> 1, lay = cell & 1;
    int ks   = (tid >> 6) & 31;

    const float* Wih = (dir ? Wih_b : Wih_f) + (size_t)lay * 2048 * 512;
    const float* Whh = (dir ? Whh_b : Whh_f) + (size_t)lay * 2048 * 512;

    int n     = hct * 16 + (l & 15);
    int grow  = g * 512 + n;
    int kbase = ks * 32 + ((l >> 4) * 8);
    const float* src = (kbase < 512) ? (Wih + (size_t)grow * 512 + kbase)
                                     : (Whh + (size_t)grow * 512 + (kbase - 512));
    __hip_bfloat16 tmp[8];
    #pragma unroll
    for (int j = 0; j < 8; ++j) tmp[j] = __float2bfloat16(src[j]);
    *reinterpret_cast<uint4*>(Wp + (size_t)tid * 8) = *reinterpret_cast<uint4*>(tmp);
}

// ---------------------------------------------------------------------------
// input [b][t][d] fp32 -> input_tb [t][b][d] bf16
// ---------------------------------------------------------------------------
__global__ void prep_input(const float* __restrict__ input, __hip_bfloat16* __restrict__ itb) {
    int tid = blockIdx.x * blockDim.x + threadIdx.x;     // 0 .. 2097151
    int dc  = tid & 63;
    int b   = (tid >> 6) & 63;
    int tau = tid >> 12;
    const float* src = input + ((size_t)b * T_ + tau) * D_ + dc * 8;
    __hip_bfloat16 tmp[8];
    #pragma unroll
    for (int j = 0; j < 8; ++j) tmp[j] = __float2bfloat16(src[j]);
    *reinterpret_cast<uint4*>(itb + ((size_t)tau * B_ + b) * D_ + dc * 8) =
        *reinterpret_cast<uint4*>(tmp);
}

// ---------------------------------------------------------------------------
// Init h_bf (parity 1) and c_f32; bias_sum = bih + bhh; zero barrier counters.
// ---------------------------------------------------------------------------
__global__ void prep_misc(const float* __restrict__ h0, const float* __restrict__ c0,
                          const float* __restrict__ bih_f, const float* __restrict__ bhh_f,
                          const float* __restrict__ bih_b, const float* __restrict__ bhh_b,
                          __hip_bfloat16* __restrict__ h_bf, float* __restrict__ c_f32,
                          float* __restrict__ bias_sum, unsigned* __restrict__ barcnt) {
    int idx = blockIdx.x * blockDim.x + threadIdx.x;
    if (idx < 2) barcnt[idx] = 0;
    if (idx < 131072) {
        int hh2 = idx & 1023;
        int b   = (idx >> 10) & 63;
        int l   = idx >> 16;
        int dir = hh2 >> 9, hh = hh2 & 511;
        h_bf[hoff(dir, l, 1) + b * H_ + hh] = __float2bfloat16(h0[idx]);
        c_f32[(((size_t)(dir * 2 + l)) * B_ + b) * H_ + hh] = c0[idx];
    } else if (idx < 131072 + 8192) {
        int i2   = idx - 131072;
        int cell = i2 >> 11, row = i2 & 2047;
        int dir  = cell >> 1, lay = cell & 1;
        const float* bi = (dir ? bih_b : bih_f) + lay * 2048;
        const float* bh = (dir ? bhh_b : bhh_f) + lay * 2048;
        bias_sum[i2] = bi[row] + bh[row];
    }
}

// ---------------------------------------------------------------------------
// Per-direction software grid barrier (256 blocks each), monotonic counter.
// __threadfence (agent acq_rel) before the add publishes this block's stores;
// after the spin it invalidates L1/L2 so subsequent plain loads see other
// XCDs' data. Bounded spin: if the barrier can't complete (co-residency
// failure), mark dead and free-run -> clean fast absmax failure, not a hang.
// ---------------------------------------------------------------------------
__device__ __forceinline__ void dir_barrier(unsigned* cnt, unsigned target, bool& alive) {
    __syncthreads();
    if (threadIdx.x == 0) {
        __threadfence();
        __hip_atomic_fetch_add(cnt, 1u, __ATOMIC_RELAXED, __HIP_MEMORY_SCOPE_AGENT);
        if (alive) {
            long long t0 = clock64();
            while (__hip_atomic_load(cnt, __ATOMIC_RELAXED, __HIP_MEMORY_SCOPE_AGENT) < target) {
                __builtin_amdgcn_s_sleep(8);
                if (clock64() - t0 > 20000000LL) { alive = false; break; }
            }
        }
        __threadfence();
    }
    __syncthreads();
}

// ---------------------------------------------------------------------------
// Persistent kernel: all 513 pipeline steps in one launch. 512 blocks x 256.
// bid = mblk*128 + cellhc; wave g holds its weight panel in 128 VGPRs.
// ---------------------------------------------------------------------------
__launch_bounds__(256, 2)
__global__ void lstm_persist(const __hip_bfloat16* __restrict__ Wp,
                             const __hip_bfloat16* __restrict__ itb,
                             __hip_bfloat16* __restrict__ h_bf,
                             float* __restrict__ c_f32, float* __restrict__ h_f32,
                             const float* __restrict__ bias_sum,
                             float* __restrict__ out,
                             unsigned* __restrict__ barcnt) {
    const int bid    = blockIdx.x;
    const int mblk   = bid >> 7;
    const int cellhc = bid & 127;
    const int cell   = cellhc >> 5;
    const int hcblk  = cellhc & 31;
    const int dir    = cell >> 1, lay = cell & 1;
    const int tid    = threadIdx.x;
    const int g      = tid >> 6, lane = tid & 63;

    __shared__ uint4 ldsA[2048];          // 32 KB: A fragments, K=1024
    __shared__ float ldsG[4][16][16];     // 4 KB: gate staging

    // ---- load this wave's weight panel into registers (128 VGPRs) ----
    uint4 wreg[32];
    {
        const uint4* wp = reinterpret_cast<const uint4*>(Wp) +
                          ((size_t)cellhc * 4 + g) * 2048 + lane;
        #pragma unroll
        for (int ks = 0; ks < 32; ++ks) wreg[ks] = wp[ks * 64];
    }

    const int hcl  = lane & 15;
    const float bsum = bias_sum[cell * 2048 + g * 512 + hcblk * 16 + hcl];

    // pointwise-element constants
    const int pm  = tid >> 4, phl = tid & 15;
    const int pb  = mblk * 16 + pm;
    const int phc = hcblk * 16 + phl;
    const size_t ci = ((size_t)cell * B_ + pb) * H_ + phc;

    unsigned* cnt = barcnt + dir;
    bool alive = true;

    for (int s = 0; s < NSTEP; ++s) {
        const int t = s - lay;
        if (t >= 0 && t < T_) {
            const int tx = dir ? (T_ - 1 - t) : t;
            // both sources have row-stride 512 (itb t-slab or h_bf slab)
            const __hip_bfloat16* src_x = lay ? (h_bf + hoff(dir, 0, t & 1))
                                              : (itb + (size_t)tx * B_ * D_);
            const __hip_bfloat16* src_h = h_bf + hoff(dir, lay, (t + 1) & 1);

            #pragma unroll
            for (int it = 0; it < 8; ++it) {
                int c   = tid + it * 256;
                int ks  = c >> 6, l = c & 63;
                int row = mblk * 16 + (l & 15);
                int k   = ks * 32 + ((l >> 4) * 8);
                const __hip_bfloat16* p = (k < 512) ? (src_x + (size_t)row * 512 + k)
                                                    : (src_h + (size_t)row * 512 + (k - 512));
                ldsA[c] = *reinterpret_cast<const uint4*>(p);
            }
            __syncthreads();

            const uint4* ap = ldsA + lane;
            f32x4 acc0 = {0.f, 0.f, 0.f, 0.f}, acc1 = {0.f, 0.f, 0.f, 0.f};
            #pragma unroll
            for (int ks = 0; ks < 32; ks += 2) {
                FragU a0, b0, a1, b1;
                a0.u = ap[ks * 64];
                b0.u = wreg[ks];
                a1.u = ap[ks * 64 + 64];
                b1.u = wreg[ks + 1];
                acc0 = __builtin_amdgcn_mfma_f32_16x16x32_bf16(a0.v, b0.v, acc0, 0, 0, 0);
                acc1 = __builtin_amdgcn_mfma_f32_16x16x32_bf16(a1.v, b1.v, acc1, 0, 0, 0);
            }

            #pragma unroll
            for (int r = 0; r < 4; ++r)
                ldsG[g][(lane >> 4) * 4 + r][hcl] = acc0[r] + acc1[r] + bsum;
            __syncthreads();

            // pointwise LSTM cell: one (b, hc) element per thread
            const float gi = ldsG[0][pm][phl];
            const float gf = ldsG[1][pm][phl];
            const float gg = ldsG[2][pm][phl];
            const float go = ldsG[3][pm][phl];
            const float cprev = c_f32[ci];
            const float si = 1.f / (1.f + expf(-gi));
            const float sf = 1.f / (1.f + expf(-gf));
            const float so = 1.f / (1.f + expf(-go));
            const float cn = sf * cprev + si * tanhf(gg);
            const float hn = so * tanhf(cn);

            c_f32[ci] = cn;
            h_bf[hoff(dir, lay, t & 1) + pb * H_ + phc] = __float2bfloat16(hn);
            if (lay)
                out[((size_t)pb * T_ + tx) * (2 * H_) + dir * H_ + phc] = hn;
            if (t == T_ - 1)
                h_f32[ci] = hn;
        }
        dir_barrier(cnt, (unsigned)(s + 1) * 256u, alive);
    }
}

// ---------------------------------------------------------------------------
__global__ void final_write(const float* __restrict__ h_f32, const float* __restrict__ c_f32,
                            float* __restrict__ out) {
    int idx = blockIdx.x * blockDim.x + threadIdx.x;   // over L*B*2H = 131072
    if (idx >= 131072) return;
    int hh2 = idx & 1023;
    int b   = (idx >> 10) & 63;
    int l   = idx >> 16;
    int dir = hh2 >> 9, hh = hh2 & 511;
    size_t ci = (((size_t)(dir * 2 + l)) * B_ + b) * H_ + hh;
    float* hout = out + (size_t)B_ * T_ * 2 * H_;
    float* cout = hout + (size_t)L_ * B_ * 2 * H_;
    hout[idx] = h_f32[ci];
    cout[idx] = c_f32[ci];
}

// ---------------------------------------------------------------------------
extern "C" void kernel_launch(void* const* d_in, const int* in_sizes, int n_in,
                              void* d_out, int out_size, void* d_ws, size_t ws_size,
                              hipStream_t stream) {
    const float* input = (const float*)d_in[0];
    const float* h0    = (const float*)d_in[1];
    const float* c0    = (const float*)d_in[2];
    const float* Wih_f = (const float*)d_in[3];
    const float* Whh_f = (const float*)d_in[4];
    const float* bih_f = (const float*)d_in[5];
    const float* bhh_f = (const float*)d_in[6];
    const float* Wih_b = (const float*)d_in[7];
    const float* Whh_b = (const float*)d_in[8];
    const float* bih_b = (const float*)d_in[9];
    const float* bhh_b = (const float*)d_in[10];
    float* out = (float*)d_out;

    char* ws = (char*)d_ws;
    __hip_bfloat16* Wp   = (__hip_bfloat16*)(ws + OFF_WP);
    __hip_bfloat16* itb  = (__hip_bfloat16*)(ws + OFF_INTB);
    __hip_bfloat16* h_bf = (__hip_bfloat16*)(ws + OFF_HBF);
    float* c_f32    = (float*)(ws + OFF_CF32);
    float* h_f32    = (float*)(ws + OFF_HF32);
    float* bias_sum = (float*)(ws + OFF_BIAS);
    unsigned* barcnt = (unsigned*)(ws + OFF_BAR);

    prep_weights<<<4096, 256, 0, stream>>>(Wih_f, Whh_f, Wih_b, Whh_b, Wp);
    prep_input  <<<8192, 256, 0, stream>>>(input, itb);
    prep_misc   <<<544, 256, 0, stream>>>(h0, c0, bih_f, bhh_f, bih_b, bhh_b,
                                          h_bf, c_f32, bias_sum, barcnt);

    lstm_persist<<<dim3(512), dim3(256), 0, stream>>>(Wp, itb, h_bf, c_f32,
                                                      h_f32, bias_sum, out, barcnt);

    final_write<<<512, 256, 0, stream>>>(h_f32, c_f32, out);
}